// Round 3
// baseline (2274.253 us; speedup 1.0000x reference)
//
#include <hip/hip_runtime.h>
#include <math.h>

// Swin block: B=32, H=W=56, C=192, NH=6, HEAD_D=32, WS=7, SS=3, N=49, NW=64, HID=768
// M = B*NW*N = 100352 window tokens (== B*3136 global tokens)

#define MTOK 100352
#define CDIM 192
#define QKVDIM 576
#define HIDDIM 768

// ---------------------------------------------------------------------------
// LN1 + cyclic shift(-3,-3) + window partition:  x[B,3136,192] -> xw[M,192]
// window token m = (bw, n); src (i,j) = ((wy*7+ny+3)%56, (wx*7+nx+3)%56)
// one wave (64 lanes) per token, 3 elems/lane
// ---------------------------------------------------------------------------
__global__ __launch_bounds__(64) void ln1_partition(
    const float* __restrict__ x, const float* __restrict__ g,
    const float* __restrict__ b, float* __restrict__ out)
{
    int m = blockIdx.x;
    int lane = threadIdx.x;
    int bw = m / 49, n = m % 49;
    int bb = bw / 64, w = bw % 64;
    int wy = w >> 3, wx = w & 7, ny = n / 7, nx = n % 7;
    int i = (wy * 7 + ny + 3) % 56;
    int j = (wx * 7 + nx + 3) % 56;
    const float* row = x + ((size_t)bb * 3136 + i * 56 + j) * CDIM;
    int c0 = lane * 3;
    float v0 = row[c0], v1 = row[c0 + 1], v2 = row[c0 + 2];
    float s = v0 + v1 + v2;
    #pragma unroll
    for (int off = 32; off; off >>= 1) s += __shfl_xor(s, off);
    float mean = s * (1.0f / 192.0f);
    float d0 = v0 - mean, d1 = v1 - mean, d2 = v2 - mean;
    float vs = d0 * d0 + d1 * d1 + d2 * d2;
    #pragma unroll
    for (int off = 32; off; off >>= 1) vs += __shfl_xor(vs, off);
    float rstd = rsqrtf(vs * (1.0f / 192.0f) + 1e-5f);
    float* orow = out + (size_t)m * CDIM;
    orow[c0 + 0] = d0 * rstd * g[c0 + 0] + b[c0 + 0];
    orow[c0 + 1] = d1 * rstd * g[c0 + 1] + b[c0 + 1];
    orow[c0 + 2] = d2 * rstd * g[c0 + 2] + b[c0 + 2];
}

// ---------------------------------------------------------------------------
// Plain LN on mc tokens:  in[mc,192] -> out[mc,192]
// ---------------------------------------------------------------------------
__global__ __launch_bounds__(64) void ln2_kernel(
    const float* __restrict__ x, const float* __restrict__ g,
    const float* __restrict__ b, float* __restrict__ out)
{
    int m = blockIdx.x;
    int lane = threadIdx.x;
    const float* row = x + (size_t)m * CDIM;
    int c0 = lane * 3;
    float v0 = row[c0], v1 = row[c0 + 1], v2 = row[c0 + 2];
    float s = v0 + v1 + v2;
    #pragma unroll
    for (int off = 32; off; off >>= 1) s += __shfl_xor(s, off);
    float mean = s * (1.0f / 192.0f);
    float d0 = v0 - mean, d1 = v1 - mean, d2 = v2 - mean;
    float vs = d0 * d0 + d1 * d1 + d2 * d2;
    #pragma unroll
    for (int off = 32; off; off >>= 1) vs += __shfl_xor(vs, off);
    float rstd = rsqrtf(vs * (1.0f / 192.0f) + 1e-5f);
    float* orow = out + (size_t)m * CDIM;
    orow[c0 + 0] = d0 * rstd * g[c0 + 0] + b[c0 + 0];
    orow[c0 + 1] = d1 * rstd * g[c0 + 1] + b[c0 + 1];
    orow[c0 + 2] = d2 * rstd * g[c0 + 2] + b[c0 + 2];
}

// ---------------------------------------------------------------------------
// fp32 tiled GEMM:  C[m,N] = A[m,K] @ W[N,K]^T + bias  (+ epilogue)
// 64x64 tile, 256 threads, 4x4 microtile. A is chunk-local (rows 0..M-1).
// EPI: 0 = bias only (qkv)            — C chunk-local
//      1 = bias + exact GELU (fc1)    — C chunk-local
//      2 = bias + window-reverse scatter + residual(res) — C,res GLOBAL bases,
//          global row = m_base + local row, scattered through shift-reverse map
//      3 = bias + residual add from res, identity rows   — C,res chunk-local
// ---------------------------------------------------------------------------
template <int EPI>
__global__ __launch_bounds__(256) void gemm_bt(
    const float* __restrict__ A, const float* __restrict__ W,
    const float* __restrict__ bias, float* __restrict__ C,
    const float* __restrict__ res, int m_base, int M, int N, int K)
{
    __shared__ float As[16][65];
    __shared__ float Bs[16][65];
    int m0 = blockIdx.x * 64, n0 = blockIdx.y * 64;
    int tid = threadIdx.x;
    int ty = tid >> 4, tx = tid & 15;
    int lrow = tid >> 2;           // 0..63
    int lkq = (tid & 3) << 2;      // 0,4,8,12
    float acc[4][4] = {};

    for (int k0 = 0; k0 < K; k0 += 16) {
        float4 av = *(const float4*)(A + (size_t)(m0 + lrow) * K + k0 + lkq);
        float4 bv = *(const float4*)(W + (size_t)(n0 + lrow) * K + k0 + lkq);
        __syncthreads();
        As[lkq + 0][lrow] = av.x; As[lkq + 1][lrow] = av.y;
        As[lkq + 2][lrow] = av.z; As[lkq + 3][lrow] = av.w;
        Bs[lkq + 0][lrow] = bv.x; Bs[lkq + 1][lrow] = bv.y;
        Bs[lkq + 2][lrow] = bv.z; Bs[lkq + 3][lrow] = bv.w;
        __syncthreads();
        #pragma unroll
        for (int kk = 0; kk < 16; kk++) {
            float a[4], bvs[4];
            #pragma unroll
            for (int i = 0; i < 4; i++) a[i] = As[kk][ty * 4 + i];
            #pragma unroll
            for (int j = 0; j < 4; j++) bvs[j] = Bs[kk][tx * 4 + j];
            #pragma unroll
            for (int i = 0; i < 4; i++)
                #pragma unroll
                for (int j = 0; j < 4; j++)
                    acc[i][j] = fmaf(a[i], bvs[j], acc[i][j]);
        }
    }

    #pragma unroll
    for (int i = 0; i < 4; i++) {
        int gm = m0 + ty * 4 + i;
        size_t orow;
        const float* rrow = nullptr;
        if (EPI == 2) {
            int gg = m_base + gm;          // global window-token row
            int bb = gg / 3136;
            int w = (gg / 49) % 64;
            int n = gg % 49;
            int gi = ((w >> 3) * 7 + n / 7 + 3) % 56;
            int gj = ((w & 7) * 7 + n % 7 + 3) % 56;
            size_t dst = (size_t)bb * 3136 + gi * 56 + gj;
            orow = dst * (size_t)N;
            rrow = res + dst * (size_t)N;
        } else {
            orow = (size_t)gm * N;
            if (EPI == 3) rrow = res + (size_t)gm * N;
        }
        #pragma unroll
        for (int j = 0; j < 4; j++) {
            int gn = n0 + tx * 4 + j;
            float val = acc[i][j] + bias[gn];
            if (EPI == 1) val = 0.5f * val * (1.0f + erff(val * 0.70710678118654752f));
            if (EPI == 2 || EPI == 3) val += rrow[gn];
            C[orow + gn] = val;
        }
    }
}

// ---------------------------------------------------------------------------
// Window attention, one block per (window, head), chunk-local.
// qkv[m,576]: q = cols [h*32..], k = cols [192+..], v = cols [384+..]
// S = q k^T / sqrt(32) + rel_bias + region_mask; softmax; O = S v
// ---------------------------------------------------------------------------
__global__ __launch_bounds__(256) void attn_kernel(
    const float* __restrict__ qkv, const float* __restrict__ bias_table,
    float* __restrict__ out)
{
    int blk = blockIdx.x;
    int h = blk % 6;
    int bw = blk / 6;          // chunk-local window id; image-aligned chunks
    int w = bw % 64;
    int wy = w >> 3, wx = w & 7;

    __shared__ float q[49][32];
    __shared__ float k[49][32];
    __shared__ float v[49][32];
    __shared__ float S[49][52];

    int tid = threadIdx.x;
    const float* base = qkv + (size_t)bw * 49 * QKVDIM;
    for (int idx = tid; idx < 1568; idx += 256) {
        int r = idx >> 5, d = idx & 31;
        q[r][d] = base[r * QKVDIM + h * 32 + d];
        k[r][d] = base[r * QKVDIM + 192 + h * 32 + d];
        v[r][d] = base[r * QKVDIM + 384 + h * 32 + d];
    }
    __syncthreads();

    const float scale = 0.17677669529663687f;  // 1/sqrt(32)
    for (int idx = tid; idx < 2401; idx += 256) {
        int n = idx / 49, mm = idx % 49;
        float s = 0.0f;
        #pragma unroll
        for (int d = 0; d < 32; d++) s = fmaf(q[n][d], k[mm][d], s);
        s *= scale;
        int ny = n / 7, nx = n % 7, my = mm / 7, mx = mm % 7;
        int rel = (ny - my + 6) * 13 + (nx - mx + 6);
        s += bias_table[rel * 6 + h];
        int gin = wy * 7 + ny, gjn = wx * 7 + nx;
        int gim = wy * 7 + my, gjm = wx * 7 + mx;
        int rn = (gin < 49 ? 0 : (gin < 53 ? 1 : 2)) * 3 + (gjn < 49 ? 0 : (gjn < 53 ? 1 : 2));
        int rm = (gim < 49 ? 0 : (gim < 53 ? 1 : 2)) * 3 + (gjm < 49 ? 0 : (gjm < 53 ? 1 : 2));
        if (rn != rm) s -= 100.0f;
        S[n][mm] = s;
    }
    __syncthreads();

    int wave = tid >> 6, lane = tid & 63;
    for (int n = wave; n < 49; n += 4) {
        float val = (lane < 49) ? S[n][lane] : -1e30f;
        float mx = val;
        #pragma unroll
        for (int off = 32; off; off >>= 1) mx = fmaxf(mx, __shfl_xor(mx, off));
        float p = (lane < 49) ? expf(val - mx) : 0.0f;
        float sum = p;
        #pragma unroll
        for (int off = 32; off; off >>= 1) sum += __shfl_xor(sum, off);
        if (lane < 49) S[n][lane] = p / sum;
    }
    __syncthreads();

    float* obase = out + (size_t)bw * 49 * CDIM + h * 32;
    for (int idx = tid; idx < 1568; idx += 256) {
        int n = idx >> 5, d = idx & 31;
        float s = 0.0f;
        #pragma unroll
        for (int mm = 0; mm < 49; mm++) s = fmaf(S[n][mm], v[mm][d], s);
        obase[n * CDIM + d] = s;
    }
}

// ---------------------------------------------------------------------------
// Workspace-adaptive schedule. xw and x_new live in d_out (disjoint phases,
// image-aligned chunks). Attention phase chunked over bc images; MLP phase
// chunked over nm row-chunks. Launch sequence depends only on ws_size
// (constant) -> graph-capture safe.
// ---------------------------------------------------------------------------
extern "C" void kernel_launch(void* const* d_in, const int* in_sizes, int n_in,
                              void* d_out, int out_size, void* d_ws, size_t ws_size,
                              hipStream_t stream)
{
    const float* x          = (const float*)d_in[0];
    const float* g1         = (const float*)d_in[1];
    const float* b1         = (const float*)d_in[2];
    const float* qkv_w      = (const float*)d_in[3];
    const float* qkv_b      = (const float*)d_in[4];
    const float* proj_w     = (const float*)d_in[5];
    const float* proj_b     = (const float*)d_in[6];
    const float* bias_table = (const float*)d_in[7];
    const float* g2         = (const float*)d_in[8];
    const float* b2         = (const float*)d_in[9];
    const float* fc1_w      = (const float*)d_in[10];
    const float* fc1_b      = (const float*)d_in[11];
    const float* fc2_w      = (const float*)d_in[12];
    const float* fc2_b      = (const float*)d_in[13];
    float* out = (float*)d_out;
    float* ws  = (float*)d_ws;

    // --- pick chunk sizes that fit ws_size ---
    // attn phase per image-chunk: bc*3136*(576+192)*4 bytes
    int bc = 32;
    while (bc > 1 && (size_t)bc * 3136 * (QKVDIM + CDIM) * 4 > ws_size) bc >>= 1;
    // mlp phase per row-chunk: mc*(192+768)*4 bytes
    int nm = 1;
    while (nm < 32 && (size_t)(MTOK / nm) * (CDIM + HIDDIM) * 4 > ws_size) nm <<= 1;

    // 1. LN1 + shift + partition -> xw in d_out [M,192]
    ln1_partition<<<MTOK, 64, 0, stream>>>(x, g1, b1, out);

    // 2-4. per image-chunk: qkv gemm, attention, proj+scatter+residual
    int Mc = bc * 3136;                       // rows per chunk
    float* qkv_c = ws;                        // [Mc,576]
    float* ao_c  = ws + (size_t)Mc * QKVDIM;  // [Mc,192]
    for (int c = 0; c < 32 / bc; c++) {
        int m_base = c * Mc;
        const float* xw_c = out + (size_t)m_base * CDIM;
        gemm_bt<0><<<dim3(Mc / 64, QKVDIM / 64), 256, 0, stream>>>(
            xw_c, qkv_w, qkv_b, qkv_c, nullptr, 0, Mc, QKVDIM, CDIM);
        attn_kernel<<<bc * 64 * 6, 256, 0, stream>>>(qkv_c, bias_table, ao_c);
        gemm_bt<2><<<dim3(Mc / 64, CDIM / 64), 256, 0, stream>>>(
            ao_c, proj_w, proj_b, out, x, m_base, Mc, CDIM, CDIM);
    }
    // d_out now holds x_new [M,192]

    // 5-7. per row-chunk: LN2, fc1+gelu, fc2+residual (in-place on d_out rows)
    int mc = MTOK / nm;
    float* ln2_c = ws;                        // [mc,192]
    float* h1_c  = ws + (size_t)mc * CDIM;    // [mc,768]
    for (int c = 0; c < nm; c++) {
        float* xr = out + (size_t)c * mc * CDIM;
        ln2_kernel<<<mc, 64, 0, stream>>>(xr, g2, b2, ln2_c);
        gemm_bt<1><<<dim3(mc / 64, HIDDIM / 64), 256, 0, stream>>>(
            ln2_c, fc1_w, fc1_b, h1_c, nullptr, 0, mc, HIDDIM, CDIM);
        gemm_bt<3><<<dim3(mc / 64, CDIM / 64), 256, 0, stream>>>(
            h1_c, fc2_w, fc2_b, xr, xr, 0, mc, CDIM, HIDDIM);
    }
}

// Round 4
// 871.752 us; speedup vs baseline: 2.6088x; 2.6088x over previous
//
#include <hip/hip_runtime.h>
#include <math.h>

// Swin block: B=32, H=W=56, C=192, NH=6, HEAD_D=32, WS=7, SS=3, N=49, NW=64, HID=768
// M = B*NW*N = 100352 window tokens

#define MTOK 100352
#define CDIM 192
#define QKVDIM 576
#define HIDDIM 768

typedef __bf16 bf16;
typedef __attribute__((ext_vector_type(8))) __bf16 bf16x8;
typedef __attribute__((ext_vector_type(4))) float f32x4;

struct __align__(4) bfpair { bf16 a, b; };

// ---------------------------------------------------------------------------
// fp32 -> bf16 weight conversion
// ---------------------------------------------------------------------------
__global__ __launch_bounds__(256) void f32_to_bf16(
    const float* __restrict__ in, bf16* __restrict__ out, int n)
{
    int i = blockIdx.x * 256 + threadIdx.x;
    if (i < n) out[i] = (bf16)in[i];
}

// ---------------------------------------------------------------------------
// LN1 + cyclic shift(-3,-3) + window partition: x[B,3136,192]f32 -> xw[M,192]bf16
// one wave per token, 3 elems/lane
// ---------------------------------------------------------------------------
__global__ __launch_bounds__(64) void ln1_partition(
    const float* __restrict__ x, const float* __restrict__ g,
    const float* __restrict__ b, bf16* __restrict__ out)
{
    int m = blockIdx.x;
    int lane = threadIdx.x;
    int bw = m / 49, n = m % 49;
    int bb = bw / 64, w = bw % 64;
    int wy = w >> 3, wx = w & 7, ny = n / 7, nx = n % 7;
    int i = (wy * 7 + ny + 3) % 56;
    int j = (wx * 7 + nx + 3) % 56;
    const float* row = x + ((size_t)bb * 3136 + i * 56 + j) * CDIM;
    int c0 = lane * 3;
    float v0 = row[c0], v1 = row[c0 + 1], v2 = row[c0 + 2];
    float s = v0 + v1 + v2;
    #pragma unroll
    for (int off = 32; off; off >>= 1) s += __shfl_xor(s, off);
    float mean = s * (1.0f / 192.0f);
    float d0 = v0 - mean, d1 = v1 - mean, d2 = v2 - mean;
    float vs = d0 * d0 + d1 * d1 + d2 * d2;
    #pragma unroll
    for (int off = 32; off; off >>= 1) vs += __shfl_xor(vs, off);
    float rstd = rsqrtf(vs * (1.0f / 192.0f) + 1e-5f);
    bf16* orow = out + (size_t)m * CDIM;
    orow[c0 + 0] = (bf16)(d0 * rstd * g[c0 + 0] + b[c0 + 0]);
    orow[c0 + 1] = (bf16)(d1 * rstd * g[c0 + 1] + b[c0 + 1]);
    orow[c0 + 2] = (bf16)(d2 * rstd * g[c0 + 2] + b[c0 + 2]);
}

// ---------------------------------------------------------------------------
// Plain LN: in[M,192]f32 -> out[M,192]bf16
// ---------------------------------------------------------------------------
__global__ __launch_bounds__(64) void ln2_kernel(
    const float* __restrict__ x, const float* __restrict__ g,
    const float* __restrict__ b, bf16* __restrict__ out)
{
    int m = blockIdx.x;
    int lane = threadIdx.x;
    const float* row = x + (size_t)m * CDIM;
    int c0 = lane * 3;
    float v0 = row[c0], v1 = row[c0 + 1], v2 = row[c0 + 2];
    float s = v0 + v1 + v2;
    #pragma unroll
    for (int off = 32; off; off >>= 1) s += __shfl_xor(s, off);
    float mean = s * (1.0f / 192.0f);
    float d0 = v0 - mean, d1 = v1 - mean, d2 = v2 - mean;
    float vs = d0 * d0 + d1 * d1 + d2 * d2;
    #pragma unroll
    for (int off = 32; off; off >>= 1) vs += __shfl_xor(vs, off);
    float rstd = rsqrtf(vs * (1.0f / 192.0f) + 1e-5f);
    bf16* orow = out + (size_t)m * CDIM;
    orow[c0 + 0] = (bf16)(d0 * rstd * g[c0 + 0] + b[c0 + 0]);
    orow[c0 + 1] = (bf16)(d1 * rstd * g[c0 + 1] + b[c0 + 1]);
    orow[c0 + 2] = (bf16)(d2 * rstd * g[c0 + 2] + b[c0 + 2]);
}

// ---------------------------------------------------------------------------
// bf16 MFMA GEMM: C[M,N] = A[M,K]bf16 @ W[N,K]^T bf16 + bias (+ epilogue)
// BM=128, BN=64, BK=64; 256 threads = 4 waves; wave w: rows w*32..w*32+31
// (2 m-frags) x 64 cols (4 n-frags) of 16x16x32 MFMA, fp32 accum.
// global_load_lds width-16 staging, double-buffered, 2-phase;
// XOR swizzle (row&7)<<4 via pre-swizzled global src + swizzled ds_read.
// EPI: 0 bias (->bf16) | 1 bias+GELU (->bf16)
//      2 bias + window-reverse scatter + residual(res) (->f32)
//      3 bias + residual (->f32, in-place rows)
// ---------------------------------------------------------------------------
template <int EPI, int OUTBF, int KDIM, int NDIM>
__global__ __launch_bounds__(256) void gemm_mfma(
    const bf16* __restrict__ A, const bf16* __restrict__ Wt,
    const float* __restrict__ bias, void* __restrict__ Cv,
    const float* __restrict__ res)
{
    __shared__ char smem[49152];  // A: 2x16KB @0, W: 2x8KB @32768
    const int tid = threadIdx.x;
    const int w = tid >> 6, l = tid & 63;
    const int m0 = blockIdx.x * 128, n0 = blockIdx.y * 64;

    // staging offsets (lds-linear o -> swizzled global src)
    int oA[4]; size_t gA[4];
    #pragma unroll
    for (int i = 0; i < 4; i++) {
        int o = i * 4096 + w * 1024 + l * 16;
        int row = o >> 7;
        int scol = (o ^ ((row & 7) << 4)) & 127;
        oA[i] = o;
        gA[i] = ((size_t)(m0 + row) * KDIM) * 2 + scol;
    }
    int oW[2]; size_t gW[2];
    #pragma unroll
    for (int i = 0; i < 2; i++) {
        int o = i * 4096 + w * 1024 + l * 16;
        int row = o >> 7;
        int scol = (o ^ ((row & 7) << 4)) & 127;
        oW[i] = o;
        gW[i] = ((size_t)(n0 + row) * KDIM) * 2 + scol;
    }

    // swizzled read offsets
    int aoff[2][2], woff[4][2];
    #pragma unroll
    for (int mf = 0; mf < 2; mf++) {
        int row = w * 32 + mf * 16 + (l & 15);
        #pragma unroll
        for (int kh = 0; kh < 2; kh++) {
            int cb = kh * 64 + (l >> 4) * 16;
            aoff[mf][kh] = row * 128 + (cb ^ ((row & 7) << 4));
        }
    }
    #pragma unroll
    for (int nf = 0; nf < 4; nf++) {
        int row = nf * 16 + (l & 15);
        #pragma unroll
        for (int kh = 0; kh < 2; kh++) {
            int cb = kh * 64 + (l >> 4) * 16;
            woff[nf][kh] = 32768 + row * 128 + (cb ^ ((row & 7) << 4));
        }
    }

    auto stage = [&](int buf, int k0) {
        const char* Ab = (const char*)A + (size_t)k0 * 2;
        #pragma unroll
        for (int i = 0; i < 4; i++)
            __builtin_amdgcn_global_load_lds(
                (const __attribute__((address_space(1))) void*)(Ab + gA[i]),
                (__attribute__((address_space(3))) void*)(smem + buf * 16384 + oA[i]),
                16, 0, 0);
        const char* Wb = (const char*)Wt + (size_t)k0 * 2;
        #pragma unroll
        for (int i = 0; i < 2; i++)
            __builtin_amdgcn_global_load_lds(
                (const __attribute__((address_space(1))) void*)(Wb + gW[i]),
                (__attribute__((address_space(3))) void*)(smem + 32768 + buf * 8192 + oW[i]),
                16, 0, 0);
    };

    f32x4 acc[2][4] = {};
    constexpr int NK = KDIM / 64;
    stage(0, 0);
    __syncthreads();
    int buf = 0;
    for (int t = 0; t < NK; ++t) {
        if (t + 1 < NK) stage(buf ^ 1, (t + 1) * 64);
        #pragma unroll
        for (int kh = 0; kh < 2; kh++) {
            bf16x8 af[2], wf[4];
            #pragma unroll
            for (int mf = 0; mf < 2; mf++)
                af[mf] = *(const bf16x8*)(smem + buf * 16384 + aoff[mf][kh]);
            #pragma unroll
            for (int nf = 0; nf < 4; nf++)
                wf[nf] = *(const bf16x8*)(smem + buf * 8192 + woff[nf][kh]);
            #pragma unroll
            for (int mf = 0; mf < 2; mf++)
                #pragma unroll
                for (int nf = 0; nf < 4; nf++)
                    acc[mf][nf] = __builtin_amdgcn_mfma_f32_16x16x32_bf16(
                        af[mf], wf[nf], acc[mf][nf], 0, 0, 0);
        }
        __syncthreads();
        buf ^= 1;
    }

    // epilogue: C/D frag layout col=lane&15, row=4*(lane>>4)+reg [m89]
    float bv[4];
    #pragma unroll
    for (int nf = 0; nf < 4; nf++) bv[nf] = bias[n0 + nf * 16 + (l & 15)];

    #pragma unroll
    for (int mf = 0; mf < 2; mf++) {
        #pragma unroll
        for (int r = 0; r < 4; r++) {
            int gm = m0 + w * 32 + mf * 16 + (l >> 4) * 4 + r;
            size_t orow;
            const float* rrow = nullptr;
            if (EPI == 2) {
                int bb = gm / 3136;
                int ww = (gm / 49) % 64;
                int n = gm % 49;
                int gi = ((ww >> 3) * 7 + n / 7 + 3) % 56;
                int gj = ((ww & 7) * 7 + n % 7 + 3) % 56;
                size_t dst = (size_t)bb * 3136 + gi * 56 + gj;
                orow = dst * NDIM;
                rrow = res + dst * NDIM;
            } else {
                orow = (size_t)gm * NDIM;
                if (EPI == 3) rrow = res + orow;
            }
            #pragma unroll
            for (int nf = 0; nf < 4; nf++) {
                int gn = n0 + nf * 16 + (l & 15);
                float v = acc[mf][nf][r] + bv[nf];
                if (EPI == 1) v = 0.5f * v * (1.0f + erff(v * 0.70710678118654752f));
                if (EPI == 2 || EPI == 3) v += rrow[gn];
                if (OUTBF) ((bf16*)Cv)[orow + gn] = (bf16)v;
                else       ((float*)Cv)[orow + gn] = v;
            }
        }
    }
}

// ---------------------------------------------------------------------------
// Window attention, one block per (window, head). bf16 I/O, fp32 compute.
// ---------------------------------------------------------------------------
__global__ __launch_bounds__(256) void attn_kernel(
    const bf16* __restrict__ qkv, const float* __restrict__ bias_table,
    bf16* __restrict__ out)
{
    int blk = blockIdx.x;
    int h = blk % 6;
    int bw = blk / 6;
    int w = bw % 64;
    int wy = w >> 3, wx = w & 7;

    __shared__ float q[49][32];
    __shared__ float k[49][32];
    __shared__ float v[49][32];
    __shared__ float S[49][52];

    int tid = threadIdx.x;
    const bf16* base = qkv + (size_t)bw * 49 * QKVDIM;
    if (tid < 196) {  // 49 rows x 4 chunks of 8
        int r = tid >> 2, dq = (tid & 3) << 3;
        const bf16* rp = base + r * QKVDIM + h * 32 + dq;
        bf16x8 qv = *(const bf16x8*)(rp);
        bf16x8 kv = *(const bf16x8*)(rp + 192);
        bf16x8 vv = *(const bf16x8*)(rp + 384);
        #pragma unroll
        for (int e = 0; e < 8; e++) {
            q[r][dq + e] = (float)qv[e];
            k[r][dq + e] = (float)kv[e];
            v[r][dq + e] = (float)vv[e];
        }
    }
    __syncthreads();

    const float scale = 0.17677669529663687f;  // 1/sqrt(32)
    for (int idx = tid; idx < 2401; idx += 256) {
        int n = idx / 49, mm = idx % 49;
        float s = 0.0f;
        #pragma unroll
        for (int d = 0; d < 32; d++) s = fmaf(q[n][d], k[mm][d], s);
        s *= scale;
        int ny = n / 7, nx = n % 7, my = mm / 7, mx = mm % 7;
        int rel = (ny - my + 6) * 13 + (nx - mx + 6);
        s += bias_table[rel * 6 + h];
        int gin = wy * 7 + ny, gjn = wx * 7 + nx;
        int gim = wy * 7 + my, gjm = wx * 7 + mx;
        int rn = (gin < 49 ? 0 : (gin < 53 ? 1 : 2)) * 3 + (gjn < 49 ? 0 : (gjn < 53 ? 1 : 2));
        int rm = (gim < 49 ? 0 : (gim < 53 ? 1 : 2)) * 3 + (gjm < 49 ? 0 : (gjm < 53 ? 1 : 2));
        if (rn != rm) s -= 100.0f;
        S[n][mm] = s;
    }
    __syncthreads();

    int wave = tid >> 6, lane = tid & 63;
    for (int n = wave; n < 49; n += 4) {
        float val = (lane < 49) ? S[n][lane] : -1e30f;
        float mx = val;
        #pragma unroll
        for (int off = 32; off; off >>= 1) mx = fmaxf(mx, __shfl_xor(mx, off));
        float p = (lane < 49) ? expf(val - mx) : 0.0f;
        float sum = p;
        #pragma unroll
        for (int off = 32; off; off >>= 1) sum += __shfl_xor(sum, off);
        if (lane < 49) S[n][lane] = p / sum;
    }
    __syncthreads();

    bf16* obase = out + (size_t)bw * 49 * CDIM + h * 32;
    for (int idx = tid; idx < 784; idx += 256) {  // 49 rows x 16 col-pairs
        int n = idx >> 4, d = (idx & 15) << 1;
        float s0 = 0.0f, s1 = 0.0f;
        #pragma unroll
        for (int mm = 0; mm < 49; mm++) {
            float p = S[n][mm];
            s0 = fmaf(p, v[mm][d], s0);
            s1 = fmaf(p, v[mm][d + 1], s1);
        }
        bfpair o; o.a = (bf16)s0; o.b = (bf16)s1;
        *(bfpair*)(obase + n * CDIM + d) = o;
    }
}

// ---------------------------------------------------------------------------
extern "C" void kernel_launch(void* const* d_in, const int* in_sizes, int n_in,
                              void* d_out, int out_size, void* d_ws, size_t ws_size,
                              hipStream_t stream)
{
    const float* x          = (const float*)d_in[0];
    const float* g1         = (const float*)d_in[1];
    const float* b1         = (const float*)d_in[2];
    const float* qkv_w      = (const float*)d_in[3];
    const float* qkv_b      = (const float*)d_in[4];
    const float* proj_w     = (const float*)d_in[5];
    const float* proj_b     = (const float*)d_in[6];
    const float* bias_table = (const float*)d_in[7];
    const float* g2         = (const float*)d_in[8];
    const float* b2         = (const float*)d_in[9];
    const float* fc1_w      = (const float*)d_in[10];
    const float* fc1_b      = (const float*)d_in[11];
    const float* fc2_w      = (const float*)d_in[12];
    const float* fc2_b      = (const float*)d_in[13];
    float* out = (float*)d_out;
    char* ws = (char*)d_ws;

    // ws layout (bytes); total 193.7 MB (ws_size >= 308 MB established round 3)
    bf16* wq   = (bf16*)(ws + 0);          // 576*192
    bf16* wp   = (bf16*)(ws + 221184);     // 192*192
    bf16* w1   = (bf16*)(ws + 294912);     // 768*192
    bf16* w2   = (bf16*)(ws + 589824);     // 192*768
    bf16* xw   = (bf16*)(ws + 1048576);                 // [M,192]  (later: ln2)
    bf16* qkvb = (bf16*)(ws + 1048576 + 38535168);      // [M,576]  (later: h1 spans this+aob)
    bf16* aob  = (bf16*)(ws + 1048576 + 154140672);     // [M,192]
    bf16* ln2b = xw;
    bf16* h1b  = qkvb;                                  // [M,768] over qkvb∪aob

    // 0. weights -> bf16
    f32_to_bf16<<<(110592 + 255) / 256, 256, 0, stream>>>(qkv_w, wq, 110592);
    f32_to_bf16<<<(36864 + 255) / 256, 256, 0, stream>>>(proj_w, wp, 36864);
    f32_to_bf16<<<(147456 + 255) / 256, 256, 0, stream>>>(fc1_w, w1, 147456);
    f32_to_bf16<<<(147456 + 255) / 256, 256, 0, stream>>>(fc2_w, w2, 147456);

    // 1. LN1 + shift + partition -> xw
    ln1_partition<<<MTOK, 64, 0, stream>>>(x, g1, b1, xw);

    // 2. qkv = xw @ qkv_w^T -> qkvb
    gemm_mfma<0, 1, 192, 576><<<dim3(MTOK / 128, 9), 256, 0, stream>>>(
        xw, wq, qkv_b, qkvb, nullptr);

    // 3. attention -> aob
    attn_kernel<<<2048 * 6, 256, 0, stream>>>(qkvb, bias_table, aob);

    // 4. proj + reverse/unshift scatter + residual(x) -> d_out (x_new, f32)
    gemm_mfma<2, 0, 192, 192><<<dim3(MTOK / 128, 3), 256, 0, stream>>>(
        aob, wp, proj_b, out, x);

    // 5. LN2(x_new) -> ln2b
    ln2_kernel<<<MTOK, 64, 0, stream>>>(out, g2, b2, ln2b);

    // 6. h1 = gelu(ln2 @ fc1_w^T) -> h1b
    gemm_mfma<1, 1, 192, 768><<<dim3(MTOK / 128, 12), 256, 0, stream>>>(
        ln2b, w1, fc1_b, h1b, nullptr);

    // 7. out = x_new + h1 @ fc2_w^T (in-place rows on d_out)
    gemm_mfma<3, 0, 768, 192><<<dim3(MTOK / 128, 3), 256, 0, stream>>>(
        h1b, w2, fc2_b, out, out);
}

// Round 5
// 561.360 us; speedup vs baseline: 4.0513x; 1.5529x over previous
//
#include <hip/hip_runtime.h>
#include <math.h>

// Swin block: B=32, H=W=56, C=192, NH=6, HEAD_D=32, WS=7, SS=3, N=49, NW=64, HID=768
// M = B*NW*N = 100352 window tokens

#define MTOK 100352
#define CDIM 192
#define QKVDIM 576
#define HIDDIM 768

typedef __bf16 bf16;
typedef __attribute__((ext_vector_type(8))) __bf16 bf16x8;
typedef __attribute__((ext_vector_type(4))) float f32x4;

// ---------------------------------------------------------------------------
// fp32 -> bf16 weight conversion
// ---------------------------------------------------------------------------
__global__ __launch_bounds__(256) void f32_to_bf16(
    const float* __restrict__ in, bf16* __restrict__ out, int n)
{
    int i = blockIdx.x * 256 + threadIdx.x;
    if (i < n) out[i] = (bf16)in[i];
}

// ---------------------------------------------------------------------------
// LN1 + cyclic shift(-3,-3) + window partition: x[B,3136,192]f32 -> xw[M,192]bf16
// 4 waves/block, one token per wave, 3 elems/lane
// ---------------------------------------------------------------------------
__global__ __launch_bounds__(256) void ln1_partition(
    const float* __restrict__ x, const float* __restrict__ g,
    const float* __restrict__ b, bf16* __restrict__ out)
{
    int m = blockIdx.x * 4 + (threadIdx.x >> 6);
    int lane = threadIdx.x & 63;
    int bw = m / 49, n = m % 49;
    int bb = bw / 64, w = bw % 64;
    int wy = w >> 3, wx = w & 7, ny = n / 7, nx = n % 7;
    int i = (wy * 7 + ny + 3) % 56;
    int j = (wx * 7 + nx + 3) % 56;
    const float* row = x + ((size_t)bb * 3136 + i * 56 + j) * CDIM;
    int c0 = lane * 3;
    float v0 = row[c0], v1 = row[c0 + 1], v2 = row[c0 + 2];
    float s = v0 + v1 + v2;
    #pragma unroll
    for (int off = 32; off; off >>= 1) s += __shfl_xor(s, off);
    float mean = s * (1.0f / 192.0f);
    float d0 = v0 - mean, d1 = v1 - mean, d2 = v2 - mean;
    float vs = d0 * d0 + d1 * d1 + d2 * d2;
    #pragma unroll
    for (int off = 32; off; off >>= 1) vs += __shfl_xor(vs, off);
    float rstd = rsqrtf(vs * (1.0f / 192.0f) + 1e-5f);
    bf16* orow = out + (size_t)m * CDIM;
    orow[c0 + 0] = (bf16)(d0 * rstd * g[c0 + 0] + b[c0 + 0]);
    orow[c0 + 1] = (bf16)(d1 * rstd * g[c0 + 1] + b[c0 + 1]);
    orow[c0 + 2] = (bf16)(d2 * rstd * g[c0 + 2] + b[c0 + 2]);
}

// ---------------------------------------------------------------------------
// Plain LN: in[M,192]f32 -> out[M,192]bf16, 4 tokens/block
// ---------------------------------------------------------------------------
__global__ __launch_bounds__(256) void ln2_kernel(
    const float* __restrict__ x, const float* __restrict__ g,
    const float* __restrict__ b, bf16* __restrict__ out)
{
    int m = blockIdx.x * 4 + (threadIdx.x >> 6);
    int lane = threadIdx.x & 63;
    const float* row = x + (size_t)m * CDIM;
    int c0 = lane * 3;
    float v0 = row[c0], v1 = row[c0 + 1], v2 = row[c0 + 2];
    float s = v0 + v1 + v2;
    #pragma unroll
    for (int off = 32; off; off >>= 1) s += __shfl_xor(s, off);
    float mean = s * (1.0f / 192.0f);
    float d0 = v0 - mean, d1 = v1 - mean, d2 = v2 - mean;
    float vs = d0 * d0 + d1 * d1 + d2 * d2;
    #pragma unroll
    for (int off = 32; off; off >>= 1) vs += __shfl_xor(vs, off);
    float rstd = rsqrtf(vs * (1.0f / 192.0f) + 1e-5f);
    bf16* orow = out + (size_t)m * CDIM;
    orow[c0 + 0] = (bf16)(d0 * rstd * g[c0 + 0] + b[c0 + 0]);
    orow[c0 + 1] = (bf16)(d1 * rstd * g[c0 + 1] + b[c0 + 1]);
    orow[c0 + 2] = (bf16)(d2 * rstd * g[c0 + 2] + b[c0 + 2]);
}

// ---------------------------------------------------------------------------
// bf16 MFMA GEMM: C[M,N] = A[M,K]bf16 @ W[N,K]^T bf16 + bias (+ epilogue)
// BM=128, BN=64, BK=64; 256 threads = 4 waves.
// EPI: 0 bias (->bf16) | 1 bias+GELU (->bf16)
//      2 bias + window-reverse scatter + residual(res) (->f32)
//      3 bias + residual (->f32, in-place rows)
// ---------------------------------------------------------------------------
template <int EPI, int OUTBF, int KDIM, int NDIM>
__global__ __launch_bounds__(256) void gemm_mfma(
    const bf16* __restrict__ A, const bf16* __restrict__ Wt,
    const float* __restrict__ bias, void* __restrict__ Cv,
    const float* __restrict__ res)
{
    __shared__ char smem[49152];  // A: 2x16KB @0, W: 2x8KB @32768
    const int tid = threadIdx.x;
    const int w = tid >> 6, l = tid & 63;
    const int m0 = blockIdx.x * 128, n0 = blockIdx.y * 64;

    int oA[4]; size_t gA[4];
    #pragma unroll
    for (int i = 0; i < 4; i++) {
        int o = i * 4096 + w * 1024 + l * 16;
        int row = o >> 7;
        int scol = (o ^ ((row & 7) << 4)) & 127;
        oA[i] = o;
        gA[i] = ((size_t)(m0 + row) * KDIM) * 2 + scol;
    }
    int oW[2]; size_t gW[2];
    #pragma unroll
    for (int i = 0; i < 2; i++) {
        int o = i * 4096 + w * 1024 + l * 16;
        int row = o >> 7;
        int scol = (o ^ ((row & 7) << 4)) & 127;
        oW[i] = o;
        gW[i] = ((size_t)(n0 + row) * KDIM) * 2 + scol;
    }

    int aoff[2][2], woff[4][2];
    #pragma unroll
    for (int mf = 0; mf < 2; mf++) {
        int row = w * 32 + mf * 16 + (l & 15);
        #pragma unroll
        for (int kh = 0; kh < 2; kh++) {
            int cb = kh * 64 + (l >> 4) * 16;
            aoff[mf][kh] = row * 128 + (cb ^ ((row & 7) << 4));
        }
    }
    #pragma unroll
    for (int nf = 0; nf < 4; nf++) {
        int row = nf * 16 + (l & 15);
        #pragma unroll
        for (int kh = 0; kh < 2; kh++) {
            int cb = kh * 64 + (l >> 4) * 16;
            woff[nf][kh] = 32768 + row * 128 + (cb ^ ((row & 7) << 4));
        }
    }

    auto stage = [&](int buf, int k0) {
        const char* Ab = (const char*)A + (size_t)k0 * 2;
        #pragma unroll
        for (int i = 0; i < 4; i++)
            __builtin_amdgcn_global_load_lds(
                (const __attribute__((address_space(1))) void*)(Ab + gA[i]),
                (__attribute__((address_space(3))) void*)(smem + buf * 16384 + oA[i]),
                16, 0, 0);
        const char* Wb = (const char*)Wt + (size_t)k0 * 2;
        #pragma unroll
        for (int i = 0; i < 2; i++)
            __builtin_amdgcn_global_load_lds(
                (const __attribute__((address_space(1))) void*)(Wb + gW[i]),
                (__attribute__((address_space(3))) void*)(smem + 32768 + buf * 8192 + oW[i]),
                16, 0, 0);
    };

    f32x4 acc[2][4] = {};
    constexpr int NK = KDIM / 64;
    stage(0, 0);
    __syncthreads();
    int buf = 0;
    for (int t = 0; t < NK; ++t) {
        if (t + 1 < NK) stage(buf ^ 1, (t + 1) * 64);
        #pragma unroll
        for (int kh = 0; kh < 2; kh++) {
            bf16x8 af[2], wf[4];
            #pragma unroll
            for (int mf = 0; mf < 2; mf++)
                af[mf] = *(const bf16x8*)(smem + buf * 16384 + aoff[mf][kh]);
            #pragma unroll
            for (int nf = 0; nf < 4; nf++)
                wf[nf] = *(const bf16x8*)(smem + buf * 8192 + woff[nf][kh]);
            #pragma unroll
            for (int mf = 0; mf < 2; mf++)
                #pragma unroll
                for (int nf = 0; nf < 4; nf++)
                    acc[mf][nf] = __builtin_amdgcn_mfma_f32_16x16x32_bf16(
                        af[mf], wf[nf], acc[mf][nf], 0, 0, 0);
        }
        __syncthreads();
        buf ^= 1;
    }

    float bv[4];
    #pragma unroll
    for (int nf = 0; nf < 4; nf++) bv[nf] = bias[n0 + nf * 16 + (l & 15)];

    #pragma unroll
    for (int mf = 0; mf < 2; mf++) {
        #pragma unroll
        for (int r = 0; r < 4; r++) {
            int gm = m0 + w * 32 + mf * 16 + (l >> 4) * 4 + r;
            size_t orow;
            const float* rrow = nullptr;
            if (EPI == 2) {
                int bb = gm / 3136;
                int ww = (gm / 49) % 64;
                int n = gm % 49;
                int gi = ((ww >> 3) * 7 + n / 7 + 3) % 56;
                int gj = ((ww & 7) * 7 + n % 7 + 3) % 56;
                size_t dst = (size_t)bb * 3136 + gi * 56 + gj;
                orow = dst * NDIM;
                rrow = res + dst * NDIM;
            } else {
                orow = (size_t)gm * NDIM;
                if (EPI == 3) rrow = res + orow;
            }
            #pragma unroll
            for (int nf = 0; nf < 4; nf++) {
                int gn = n0 + nf * 16 + (l & 15);
                float v = acc[mf][nf][r] + bv[nf];
                if (EPI == 1) v = 0.5f * v * (1.0f + erff(v * 0.70710678118654752f));
                if (EPI == 2 || EPI == 3) v += rrow[gn];
                if (OUTBF) ((bf16*)Cv)[orow + gn] = (bf16)v;
                else       ((float*)Cv)[orow + gn] = v;
            }
        }
    }
}

// ---------------------------------------------------------------------------
// MFMA window attention. One WAVE per (window, head); 4 independent waves
// per block, no barriers. 12288 waves -> 3072 blocks.
// Frag layouts identical to gemm_mfma (A/B: row=l&15, k=8*(l>>4)+j;
// D: row=4*(l>>4)+reg, col=l&15).
// Token dim padded 49->64 by clamping loads to token 48; pad k-cols masked
// to -1e30 (P=0), pad q-rows computed but never stored.
// Per-wave LDS (13568 B): P[64][64]bf16 swizzled ^(q&7)<<4, vT[32][72]bf16,
// bias[176]f32.
// ---------------------------------------------------------------------------
__global__ __launch_bounds__(256) void attn_mfma(
    const bf16* __restrict__ qkv, const float* __restrict__ bias_table,
    bf16* __restrict__ out)
{
    __shared__ char smem[54272];
    const int tid = threadIdx.x;
    const int wv = tid >> 6, l = tid & 63;
    const int g = l >> 4, l15 = l & 15;
    const int gw = blockIdx.x * 4 + wv;
    const int win = gw / 6, h = gw % 6;
    const int w64 = win & 63;
    const int wy = w64 >> 3, wx = w64 & 7;

    char* wbase = smem + wv * 13568;
    char* Pb  = wbase;                       // 8192: P[64][64] bf16 swizzled
    char* vTb = wbase + 8192;                // 4608: vT[32][72] bf16
    float* biasL = (float*)(wbase + 12800);  // 169 f32

    // bias table slice -> LDS
    #pragma unroll
    for (int i = 0; i < 3; i++) {
        int idx = l + 64 * i;
        if (idx < 169) biasL[idx] = bias_table[idx * 6 + h];
    }

    const bf16* wqkv = qkv + (size_t)win * 49 * QKVDIM;

    // V load (coalesced rows) -> vT[d][t] transposed
    #pragma unroll
    for (int nt = 0; nt < 4; nt++) {
        int t = 16 * nt + l15;
        int tc = t > 48 ? 48 : t;
        bf16x8 vf = *(const bf16x8*)(wqkv + (size_t)tc * QKVDIM + 384 + h * 32 + 8 * g);
        #pragma unroll
        for (int j = 0; j < 8; j++)
            *(bf16*)(vTb + (8 * g + j) * 144 + t * 2) = vf[j];
    }

    // Q,K fragments direct from global (16B/lane)
    bf16x8 Qf[4], Kf[4];
    #pragma unroll
    for (int i = 0; i < 4; i++) {
        int t = 16 * i + l15;
        int tc = t > 48 ? 48 : t;
        const bf16* rp = wqkv + (size_t)tc * QKVDIM + h * 32 + 8 * g;
        Qf[i] = *(const bf16x8*)(rp);
        Kf[i] = *(const bf16x8*)(rp + 192);
    }

    // S = Q K^T : 16 MFMA, acc[mt][nt] row=q col=k
    f32x4 accS[4][4] = {};
    #pragma unroll
    for (int mt = 0; mt < 4; mt++)
        #pragma unroll
        for (int nt = 0; nt < 4; nt++)
            accS[mt][nt] = __builtin_amdgcn_mfma_f32_16x16x32_bf16(
                Qf[mt], Kf[nt], accS[mt][nt], 0, 0, 0);

    // k-side geometry (cols k = 16nt + l15)
    int kyv[4], kxv[4], kreg[4]; bool kok[4];
    #pragma unroll
    for (int nt = 0; nt < 4; nt++) {
        int kc = 16 * nt + l15;
        kok[nt] = kc < 49;
        int kcc = kc > 48 ? 48 : kc;
        kyv[nt] = kcc / 7; kxv[nt] = kcc % 7;
        int gi = wy * 7 + kyv[nt], gj = wx * 7 + kxv[nt];
        kreg[nt] = (gi < 49 ? 0 : (gi < 53 ? 1 : 2)) * 3 + (gj < 49 ? 0 : (gj < 53 ? 1 : 2));
    }

    // scale + bias + mask, row softmax (rows on l&15-groups via shfl 1/2/4/8),
    // unnormalized P -> LDS bf16 (swizzled); keep inv[mt][r]
    const float scale = 0.17677669529663687f;  // 1/sqrt(32)
    float inv[4][4];
    #pragma unroll
    for (int mt = 0; mt < 4; mt++) {
        #pragma unroll
        for (int r = 0; r < 4; r++) {
            int q = 16 * mt + 4 * g + r;
            int qq = q > 48 ? 48 : q;
            int qy = qq / 7, qx = qq % 7;
            int gi = wy * 7 + qy, gj = wx * 7 + qx;
            int qreg = (gi < 49 ? 0 : (gi < 53 ? 1 : 2)) * 3 + (gj < 49 ? 0 : (gj < 53 ? 1 : 2));
            float vals[4];
            float vmax = -3e38f;
            #pragma unroll
            for (int nt = 0; nt < 4; nt++) {
                float v = accS[mt][nt][r] * scale
                        + biasL[(qy - kyv[nt] + 6) * 13 + (qx - kxv[nt] + 6)];
                if (qreg != kreg[nt]) v -= 100.0f;
                if (!kok[nt]) v = -1e30f;
                vals[nt] = v;
                vmax = fmaxf(vmax, v);
            }
            vmax = fmaxf(vmax, __shfl_xor(vmax, 1));
            vmax = fmaxf(vmax, __shfl_xor(vmax, 2));
            vmax = fmaxf(vmax, __shfl_xor(vmax, 4));
            vmax = fmaxf(vmax, __shfl_xor(vmax, 8));
            float ssum = 0.0f;
            #pragma unroll
            for (int nt = 0; nt < 4; nt++) {
                float p = __expf(vals[nt] - vmax);
                ssum += p;
                int byte = q * 128 + (16 * nt + l15) * 2;
                byte ^= (q & 7) << 4;
                *(bf16*)(Pb + byte) = (bf16)p;
            }
            ssum += __shfl_xor(ssum, 1);
            ssum += __shfl_xor(ssum, 2);
            ssum += __shfl_xor(ssum, 4);
            ssum += __shfl_xor(ssum, 8);
            inv[mt][r] = 1.0f / ssum;
        }
    }

    // O = P V : 16 MFMA. P as A-frag from LDS (swizzled b128), Vt as B-frag.
    f32x4 accO[4][2] = {};
    #pragma unroll
    for (int ks = 0; ks < 2; ks++) {
        bf16x8 Vt[2];
        #pragma unroll
        for (int dt = 0; dt < 2; dt++)
            Vt[dt] = *(const bf16x8*)(vTb + (16 * dt + l15) * 144 + 64 * ks + 16 * g);
        #pragma unroll
        for (int mt = 0; mt < 4; mt++) {
            int q = 16 * mt + l15;
            int byte = q * 128 + ((64 * ks + 16 * g) ^ ((q & 7) << 4));
            bf16x8 Pf = *(const bf16x8*)(Pb + byte);
            #pragma unroll
            for (int dt = 0; dt < 2; dt++)
                accO[mt][dt] = __builtin_amdgcn_mfma_f32_16x16x32_bf16(
                    Pf, Vt[dt], accO[mt][dt], 0, 0, 0);
        }
    }

    // store (normalize by inv; skip pad q-rows)
    bf16* obase = out + (size_t)win * 49 * CDIM + h * 32;
    #pragma unroll
    for (int mt = 0; mt < 4; mt++)
        #pragma unroll
        for (int r = 0; r < 4; r++) {
            int q = 16 * mt + 4 * g + r;
            if (q < 49) {
                #pragma unroll
                for (int dt = 0; dt < 2; dt++) {
                    float v = accO[mt][dt][r] * inv[mt][r];
                    obase[(size_t)q * CDIM + 16 * dt + l15] = (bf16)v;
                }
            }
        }
}

// ---------------------------------------------------------------------------
extern "C" void kernel_launch(void* const* d_in, const int* in_sizes, int n_in,
                              void* d_out, int out_size, void* d_ws, size_t ws_size,
                              hipStream_t stream)
{
    const float* x          = (const float*)d_in[0];
    const float* g1         = (const float*)d_in[1];
    const float* b1         = (const float*)d_in[2];
    const float* qkv_w      = (const float*)d_in[3];
    const float* qkv_b      = (const float*)d_in[4];
    const float* proj_w     = (const float*)d_in[5];
    const float* proj_b     = (const float*)d_in[6];
    const float* bias_table = (const float*)d_in[7];
    const float* g2         = (const float*)d_in[8];
    const float* b2         = (const float*)d_in[9];
    const float* fc1_w      = (const float*)d_in[10];
    const float* fc1_b      = (const float*)d_in[11];
    const float* fc2_w      = (const float*)d_in[12];
    const float* fc2_b      = (const float*)d_in[13];
    float* out = (float*)d_out;
    char* ws = (char*)d_ws;

    // ws layout (bytes); total ~194 MB (ws >= 308 MB established round 3)
    bf16* wq   = (bf16*)(ws + 0);          // 576*192
    bf16* wp   = (bf16*)(ws + 221184);     // 192*192
    bf16* w1   = (bf16*)(ws + 294912);     // 768*192
    bf16* w2   = (bf16*)(ws + 589824);     // 192*768
    bf16* xw   = (bf16*)(ws + 1048576);                 // [M,192] (later: ln2)
    bf16* qkvb = (bf16*)(ws + 1048576 + 38535168);      // [M,576] (later: h1 part)
    bf16* aob  = (bf16*)(ws + 1048576 + 154140672);     // [M,192]
    bf16* ln2b = xw;
    bf16* h1b  = qkvb;                                  // [M,768] over qkvb∪aob

    // 0. weights -> bf16
    f32_to_bf16<<<(110592 + 255) / 256, 256, 0, stream>>>(qkv_w, wq, 110592);
    f32_to_bf16<<<(36864 + 255) / 256, 256, 0, stream>>>(proj_w, wp, 36864);
    f32_to_bf16<<<(147456 + 255) / 256, 256, 0, stream>>>(fc1_w, w1, 147456);
    f32_to_bf16<<<(147456 + 255) / 256, 256, 0, stream>>>(fc2_w, w2, 147456);

    // 1. LN1 + shift + partition -> xw
    ln1_partition<<<MTOK / 4, 256, 0, stream>>>(x, g1, b1, xw);

    // 2. qkv = xw @ qkv_w^T -> qkvb
    gemm_mfma<0, 1, 192, 576><<<dim3(MTOK / 128, 9), 256, 0, stream>>>(
        xw, wq, qkv_b, qkvb, nullptr);

    // 3. MFMA attention -> aob
    attn_mfma<<<3072, 256, 0, stream>>>(qkvb, bias_table, aob);

    // 4. proj + reverse/unshift scatter + residual(x) -> d_out (x_new, f32)
    gemm_mfma<2, 0, 192, 192><<<dim3(MTOK / 128, 3), 256, 0, stream>>>(
        aob, wp, proj_b, out, x);

    // 5. LN2(x_new) -> ln2b
    ln2_kernel<<<MTOK / 4, 256, 0, stream>>>(out, g2, b2, ln2b);

    // 6. h1 = gelu(ln2 @ fc1_w^T) -> h1b
    gemm_mfma<1, 1, 192, 768><<<dim3(MTOK / 128, 12), 256, 0, stream>>>(
        ln2b, w1, fc1_b, h1b, nullptr);

    // 7. out = x_new + h1 @ fc2_w^T (in-place rows on d_out)
    gemm_mfma<3, 0, 768, 192><<<dim3(MTOK / 128, 3), 256, 0, stream>>>(
        h1b, w2, fc2_b, out, out);
}